// Round 1
// baseline (8662.848 us; speedup 1.0000x reference)
//
#include <hip/hip_runtime.h>
#include <hip/hip_bf16.h>

// Problem: B=64, S=512, I=256, H=512 LSTM forward.
// Strategy: persistent kernel, 64 co-resident WGs, one device-scope atomic
// barrier per timestep. Each WG owns 8 hidden units (32 gate cols), U/W
// slices live in LDS (bf16, transposed for MFMA B-frags), c in registers,
// h double-buffered bf16 in ws. x@W fused into the step (K=256+512=768).

#define BB 64
#define SS 512
#define II 256
#define HH 512
#define G4 2048
#define NWG 64
#define HJ 8    // hidden units per WG
#define NC 32   // gate columns per WG = 4*HJ

typedef __attribute__((ext_vector_type(8))) short bf16x8;
typedef __attribute__((ext_vector_type(4))) float f32x4;

// x [b][t][i] fp32 -> xb [t][b][i] bf16 (per-step A-operand layout)
__global__ void convert_x_kernel(const float* __restrict__ x,
                                 __hip_bfloat16* __restrict__ xb) {
  int blk = blockIdx.x;          // b*SS + t
  int b = blk >> 9;
  int t = blk & (SS - 1);
  int i = threadIdx.x;           // 0..255
  float v = x[(size_t)blk * II + i];
  xb[((size_t)t * BB + b) * II + i] = __float2bfloat16(v);
}

__global__ __launch_bounds__(256, 1)
void lstm_persistent(const float* __restrict__ W,
                     const float* __restrict__ U,
                     const float* __restrict__ bias,
                     const __hip_bfloat16* __restrict__ xb,
                     __hip_bfloat16* __restrict__ hbuf,   // [2][BB][HH]
                     unsigned int* __restrict__ ctr,
                     float* __restrict__ out) {
  // LDS: Ut 33.3KB + Wt 16.9KB + gate 8.4KB + bias -> ~59KB (<160KB)
  // rows padded +8 bf16: row stride 260/132 dwords -> bank advance 4/lane,
  // ds_read_b128 2-way aliasing only (free per m136).
  __shared__ alignas(16) __hip_bfloat16 Ut[NC][HH + 8];
  __shared__ alignas(16) __hip_bfloat16 Wt[NC][II + 8];
  __shared__ float gate[BB][NC + 1];   // +1 pad: 4-way -> 2-way on scatter
  __shared__ float bia[NC];

  const int tid = threadIdx.x;
  const int wg = blockIdx.x;
  const int j0 = wg * HJ;

  // ---- one-time: stage U/W column slices (transposed, bf16) ----
  // col c in [0,32): gate g=c>>3, unit j=c&7, global col n = g*HH + j0 + j
  for (int idx = tid; idx < NC * HH; idx += 256) {
    int c = idx & (NC - 1);
    int k = idx >> 5;
    int g = c >> 3, j = c & 7;
    Ut[c][k] = __float2bfloat16(U[(size_t)k * G4 + g * HH + j0 + j]);
  }
  for (int idx = tid; idx < NC * II; idx += 256) {
    int c = idx & (NC - 1);
    int k = idx >> 5;
    int g = c >> 3, j = c & 7;
    Wt[c][k] = __float2bfloat16(W[(size_t)k * G4 + g * HH + j0 + j]);
  }
  if (tid < NC) {
    int g = tid >> 3, j = tid & 7;
    bia[tid] = bias[g * HH + j0 + j];
  }
  __syncthreads();

  const int wave = tid >> 6;       // M-tile (16 batches each)
  const int lane = tid & 63;
  const int l16 = lane & 15;
  const int quad = lane >> 4;
  const int arow = wave * 16 + l16;  // batch row for A-fragment

  // per-thread cell state: thread owns pairs p = 2*tid, 2*tid+1 ; b=p>>3, j=p&7
  float c0 = 0.f, c1 = 0.f;
  const int pb0 = (2 * tid) >> 3, pj0 = (2 * tid) & 7;
  const int pb1 = (2 * tid + 1) >> 3, pj1 = (2 * tid + 1) & 7;

  for (int t = 0; t < SS; ++t) {
    const __hip_bfloat16* hread = hbuf + (size_t)((t & 1) ^ 1) * (BB * HH);
    __hip_bfloat16* hwrite = hbuf + (size_t)(t & 1) * (BB * HH);
    const __hip_bfloat16* xt = xb + (size_t)t * (BB * II);

    f32x4 acc0 = {0.f, 0.f, 0.f, 0.f};  // N-tile 0 (cols 0..15: gates i,f)
    f32x4 acc1 = {0.f, 0.f, 0.f, 0.f};  // N-tile 1 (cols 16..31: gates g,o)

    // x @ W : K=256 -> 8 k-steps. A[m=lane&15][k=quad*8+j] (verified m120).
#pragma unroll
    for (int ks = 0; ks < II / 32; ++ks) {
      bf16x8 a = *(const bf16x8*)(xt + (size_t)arow * II + ks * 32 + quad * 8);
      bf16x8 fb0 = *(const bf16x8*)(&Wt[l16][ks * 32 + quad * 8]);
      bf16x8 fb1 = *(const bf16x8*)(&Wt[16 + l16][ks * 32 + quad * 8]);
      acc0 = __builtin_amdgcn_mfma_f32_16x16x32_bf16(a, fb0, acc0, 0, 0, 0);
      acc1 = __builtin_amdgcn_mfma_f32_16x16x32_bf16(a, fb1, acc1, 0, 0, 0);
    }
    // h @ U : K=512 -> 16 k-steps
#pragma unroll 4
    for (int ks = 0; ks < HH / 32; ++ks) {
      bf16x8 a = *(const bf16x8*)(hread + (size_t)arow * HH + ks * 32 + quad * 8);
      bf16x8 fb0 = *(const bf16x8*)(&Ut[l16][ks * 32 + quad * 8]);
      bf16x8 fb1 = *(const bf16x8*)(&Ut[16 + l16][ks * 32 + quad * 8]);
      acc0 = __builtin_amdgcn_mfma_f32_16x16x32_bf16(a, fb0, acc0, 0, 0, 0);
      acc1 = __builtin_amdgcn_mfma_f32_16x16x32_bf16(a, fb1, acc1, 0, 0, 0);
    }

    // D layout (verified m89): row = quad*4 + reg, col = lane&15
#pragma unroll
    for (int r = 0; r < 4; ++r) {
      int row = wave * 16 + quad * 4 + r;
      gate[row][l16] = acc0[r];
      gate[row][16 + l16] = acc1[r];
    }
    __syncthreads();

    // ---- elementwise cell update: 512 (b,j) pairs over 256 threads ----
    auto cell = [&](int b, int j, float& cst) {
      float xi = gate[b][j] + bia[j];
      float xf = gate[b][8 + j] + bia[8 + j];
      float xg = gate[b][16 + j] + bia[16 + j];
      float xo = gate[b][24 + j] + bia[24 + j];
      float it = 1.f / (1.f + __expf(-xi));
      float ft = 1.f / (1.f + __expf(-xf));
      float gx = fminf(fmaxf(xg, -15.f), 15.f);   // clamp: avoid inf/inf NaN
      float eg = __expf(2.f * gx);
      float gt = (eg - 1.f) / (eg + 1.f);
      float ot = 1.f / (1.f + __expf(-xo));
      cst = ft * cst + it * gt;
      float cc = fminf(fmaxf(cst, -15.f), 15.f);
      float ec = __expf(2.f * cc);
      float th = (ec - 1.f) / (ec + 1.f);
      float h = ot * th;
      hwrite[(size_t)b * HH + j0 + j] = __float2bfloat16(h);
      out[(size_t)b * (SS * HH) + (size_t)t * HH + j0 + j] = h;
      if (t == SS - 1) {
        out[(size_t)(BB * SS * HH) + (size_t)b * HH + j0 + j] = h;       // h_f
        out[(size_t)(BB * SS * HH) + (size_t)(BB * HH) + (size_t)b * HH + j0 + j] = cst; // c_f
      }
    };
    cell(pb0, pj0, c0);
    cell(pb1, pj1, c1);

    // ---- device-wide barrier (one per step; h double-buffered so one
    // barrier suffices: reads of h(t-1) happen-before arrive(t), writes of
    // h(t+1) happen-after wait(t)) ----
    if (t < SS - 1) {
      __threadfence();   // release: drain+publish this thread's h stores
      __syncthreads();
      if (tid == 0) {
        __hip_atomic_fetch_add(ctr, 1u, __ATOMIC_RELEASE,
                               __HIP_MEMORY_SCOPE_AGENT);
        unsigned target = (unsigned)(t + 1) * NWG;
        while (__hip_atomic_load(ctr, __ATOMIC_ACQUIRE,
                                 __HIP_MEMORY_SCOPE_AGENT) < target) {
          __builtin_amdgcn_s_sleep(1);
        }
      }
      __syncthreads();
      __threadfence();   // acquire side: invalidate stale L1/L2 lines
    }
  }
}

extern "C" void kernel_launch(void* const* d_in, const int* in_sizes, int n_in,
                              void* d_out, int out_size, void* d_ws, size_t ws_size,
                              hipStream_t stream) {
  const float* x = (const float*)d_in[0];     // [64,512,256]
  const float* W = (const float*)d_in[1];     // [256,2048]
  const float* U = (const float*)d_in[2];     // [512,2048]
  const float* bias = (const float*)d_in[3];  // [2048]
  float* out = (float*)d_out;

  char* ws = (char*)d_ws;
  unsigned int* ctr = (unsigned int*)ws;                       // [0,256)
  __hip_bfloat16* hbuf = (__hip_bfloat16*)(ws + 256);          // 2*64*512*2 = 128KB
  __hip_bfloat16* xb =
      (__hip_bfloat16*)(ws + 256 + 2 * BB * HH * sizeof(__hip_bfloat16)); // 16MB
  // ws total ~16.2 MB; ws is re-poisoned to 0xAA each launch -> zero sync+h
  hipMemsetAsync(d_ws, 0, 256 + 2 * BB * HH * sizeof(__hip_bfloat16), stream);

  convert_x_kernel<<<BB * SS, II, 0, stream>>>(x, xb);
  lstm_persistent<<<NWG, 256, 0, stream>>>(W, U, bias, xb, hbuf, ctr, out);
}

// Round 2
// 3287.602 us; speedup vs baseline: 2.6350x; 2.6350x over previous
//
#include <hip/hip_runtime.h>
#include <hip/hip_bf16.h>

// Problem: B=64, S=512, I=256, H=512 LSTM forward.
// R2: persistent kernel, 64 WGs, one LLC-coherent barrier per step.
// Key change vs R1: NO __threadfence / NO acquire-release atomics (those emit
// buffer_wbl2/buffer_inv = full per-XCD-L2 writeback/invalidate per use, which
// cost ~16 us/step). Instead all cross-WG data (h) moves through the LLC via
// sc1 relaxed agent-scope atomic stores/loads; the barrier is a relaxed
// fetch_add + relaxed poll. __syncthreads() before the arrive drains each
// wave's vmcnt (compiler emits s_waitcnt vmcnt(0) before s_barrier), so h
// stores are globally visible at the LLC before the counter bump.

#define BB 64
#define SS 512
#define II 256
#define HH 512
#define G4 2048
#define NWG 64
#define HJ 8    // hidden units per WG
#define NC 32   // gate columns per WG = 4*HJ

typedef __attribute__((ext_vector_type(8))) short bf16x8;
typedef __attribute__((ext_vector_type(4))) float f32x4;

// x [b][t][i] fp32 -> xb [t][b][i] bf16 (per-step A-operand layout)
__global__ void convert_x_kernel(const float* __restrict__ x,
                                 __hip_bfloat16* __restrict__ xb) {
  int blk = blockIdx.x;          // b*SS + t
  int b = blk >> 9;
  int t = blk & (SS - 1);
  int i = threadIdx.x;           // 0..255
  float v = x[(size_t)blk * II + i];
  xb[((size_t)t * BB + b) * II + i] = __float2bfloat16(v);
}

// LLC-coherent (agent-scope, sc1) relaxed accessors — no cache maintenance.
__device__ __forceinline__ unsigned long long ld_llc_u64(const void* p) {
  return __hip_atomic_load((unsigned long long*)p, __ATOMIC_RELAXED,
                           __HIP_MEMORY_SCOPE_AGENT);
}
__device__ __forceinline__ bf16x8 ld_llc_bf16x8(const __hip_bfloat16* p) {
  union { unsigned long long q[2]; bf16x8 v; } u;
  u.q[0] = ld_llc_u64(p);
  u.q[1] = ld_llc_u64(p + 4);   // +8 bytes
  return u.v;
}
__device__ __forceinline__ void st_llc_u32(unsigned int* p, unsigned int v) {
  __hip_atomic_store(p, v, __ATOMIC_RELAXED, __HIP_MEMORY_SCOPE_AGENT);
}

__global__ __launch_bounds__(256, 1)
void lstm_persistent(const float* __restrict__ W,
                     const float* __restrict__ U,
                     const float* __restrict__ bias,
                     const __hip_bfloat16* __restrict__ xb,
                     __hip_bfloat16* __restrict__ hbuf,   // [2][BB][HH]
                     unsigned int* __restrict__ ctr,
                     float* __restrict__ out) {
  __shared__ alignas(16) __hip_bfloat16 Ut[NC][HH + 8];
  __shared__ alignas(16) __hip_bfloat16 Wt[NC][II + 8];
  __shared__ float gate[BB][NC + 1];
  __shared__ float bia[NC];

  const int tid = threadIdx.x;
  const int wg = blockIdx.x;
  const int j0 = wg * HJ;

  // ---- one-time: stage U/W column slices (transposed, bf16) ----
  for (int idx = tid; idx < NC * HH; idx += 256) {
    int c = idx & (NC - 1);
    int k = idx >> 5;
    int g = c >> 3, j = c & 7;
    Ut[c][k] = __float2bfloat16(U[(size_t)k * G4 + g * HH + j0 + j]);
  }
  for (int idx = tid; idx < NC * II; idx += 256) {
    int c = idx & (NC - 1);
    int k = idx >> 5;
    int g = c >> 3, j = c & 7;
    Wt[c][k] = __float2bfloat16(W[(size_t)k * G4 + g * HH + j0 + j]);
  }
  if (tid < NC) {
    int g = tid >> 3, j = tid & 7;
    bia[tid] = bias[g * HH + j0 + j];
  }
  __syncthreads();

  const int wave = tid >> 6;
  const int lane = tid & 63;
  const int l16 = lane & 15;
  const int quad = lane >> 4;
  const int arow = wave * 16 + l16;   // batch row for A-fragment

  // per-thread cell state: pairs p = 2*tid, 2*tid+1 share b; j consecutive
  float c0 = 0.f, c1 = 0.f;
  const int pb = (2 * tid) >> 3;      // batch
  const int pj = (2 * tid) & 7;       // even unit index; pair is (pj, pj+1)

  for (int t = 0; t < SS; ++t) {
    const __hip_bfloat16* xt = xb + (size_t)t * (BB * II);

    f32x4 acc0 = {0.f, 0.f, 0.f, 0.f};  // cols 0..15  (gates i,f)
    f32x4 acc1 = {0.f, 0.f, 0.f, 0.f};  // cols 16..31 (gates g,o)

    // ---- x @ W : independent of h(t-1) -> do BEFORE the barrier wait ----
#pragma unroll
    for (int ks = 0; ks < II / 32; ++ks) {
      bf16x8 a = *(const bf16x8*)(xt + (size_t)arow * II + ks * 32 + quad * 8);
      bf16x8 fb0 = *(const bf16x8*)(&Wt[l16][ks * 32 + quad * 8]);
      bf16x8 fb1 = *(const bf16x8*)(&Wt[16 + l16][ks * 32 + quad * 8]);
      acc0 = __builtin_amdgcn_mfma_f32_16x16x32_bf16(a, fb0, acc0, 0, 0, 0);
      acc1 = __builtin_amdgcn_mfma_f32_16x16x32_bf16(a, fb1, acc1, 0, 0, 0);
    }

    // ---- wait: all WGs published h(t-1) (relaxed poll, no cache ops) ----
    if (t > 0) {
      if (tid == 0) {
        unsigned target = (unsigned)t * NWG;
        while (__hip_atomic_load(ctr, __ATOMIC_RELAXED,
                                 __HIP_MEMORY_SCOPE_AGENT) < target) {
          __builtin_amdgcn_s_sleep(1);
        }
      }
      __syncthreads();
    }

    const __hip_bfloat16* hread = hbuf + (size_t)((t & 1) ^ 1) * (BB * HH);
    __hip_bfloat16* hwrite = hbuf + (size_t)(t & 1) * (BB * HH);

    // ---- h @ U : sc1 loads (LLC-coherent) ----
#pragma unroll 4
    for (int ks = 0; ks < HH / 32; ++ks) {
      bf16x8 a = ld_llc_bf16x8(hread + (size_t)arow * HH + ks * 32 + quad * 8);
      bf16x8 fb0 = *(const bf16x8*)(&Ut[l16][ks * 32 + quad * 8]);
      bf16x8 fb1 = *(const bf16x8*)(&Ut[16 + l16][ks * 32 + quad * 8]);
      acc0 = __builtin_amdgcn_mfma_f32_16x16x32_bf16(a, fb0, acc0, 0, 0, 0);
      acc1 = __builtin_amdgcn_mfma_f32_16x16x32_bf16(a, fb1, acc1, 0, 0, 0);
    }

    // D layout (verified m89): row = quad*4 + reg, col = lane&15
#pragma unroll
    for (int r = 0; r < 4; ++r) {
      int row = wave * 16 + quad * 4 + r;
      gate[row][l16] = acc0[r];
      gate[row][16 + l16] = acc1[r];
    }
    __syncthreads();

    // ---- elementwise cell update: 2 (b,j) pairs per thread ----
    float hv[2];
#pragma unroll
    for (int s = 0; s < 2; ++s) {
      int j = pj + s;
      float& cst = s ? c1 : c0;
      float xi = gate[pb][j] + bia[j];
      float xf = gate[pb][8 + j] + bia[8 + j];
      float xg = gate[pb][16 + j] + bia[16 + j];
      float xo = gate[pb][24 + j] + bia[24 + j];
      float it = 1.f / (1.f + __expf(-xi));
      float ft = 1.f / (1.f + __expf(-xf));
      float gx = fminf(fmaxf(xg, -15.f), 15.f);
      float eg = __expf(2.f * gx);
      float gt = (eg - 1.f) / (eg + 1.f);
      float ot = 1.f / (1.f + __expf(-xo));
      cst = ft * cst + it * gt;
      float cc = fminf(fmaxf(cst, -15.f), 15.f);
      float ec = __expf(2.f * cc);
      float th = (ec - 1.f) / (ec + 1.f);
      hv[s] = ot * th;
    }
    // publish h(t): packed 2xbf16 via sc1 relaxed atomic store
    union { __hip_bfloat16 b[2]; unsigned int u; } hp;
    hp.b[0] = __float2bfloat16(hv[0]);
    hp.b[1] = __float2bfloat16(hv[1]);
    st_llc_u32((unsigned int*)(hwrite + (size_t)pb * HH + j0 + pj), hp.u);
    // hidden_seq output (plain stores; flushed at kernel end)
    *(float2*)(out + (size_t)pb * (SS * HH) + (size_t)t * HH + j0 + pj) =
        make_float2(hv[0], hv[1]);
    if (t == SS - 1) {
      size_t base = (size_t)BB * SS * HH;
      *(float2*)(out + base + (size_t)pb * HH + j0 + pj) =
          make_float2(hv[0], hv[1]);                       // h_f
      *(float2*)(out + base + (size_t)BB * HH + (size_t)pb * HH + j0 + pj) =
          make_float2(c0, c1);                             // c_f
    }

    // ---- arrive: syncthreads drains all waves' vmcnt, then one relaxed add
    if (t < SS - 1) {
      __syncthreads();
      if (tid == 0) {
        __hip_atomic_fetch_add(ctr, 1u, __ATOMIC_RELAXED,
                               __HIP_MEMORY_SCOPE_AGENT);
      }
    }
  }
}

extern "C" void kernel_launch(void* const* d_in, const int* in_sizes, int n_in,
                              void* d_out, int out_size, void* d_ws, size_t ws_size,
                              hipStream_t stream) {
  const float* x = (const float*)d_in[0];     // [64,512,256]
  const float* W = (const float*)d_in[1];     // [256,2048]
  const float* U = (const float*)d_in[2];     // [512,2048]
  const float* bias = (const float*)d_in[3];  // [2048]
  float* out = (float*)d_out;

  char* ws = (char*)d_ws;
  unsigned int* ctr = (unsigned int*)ws;                       // [0,256)
  __hip_bfloat16* hbuf = (__hip_bfloat16*)(ws + 256);          // 128 KB
  __hip_bfloat16* xb =
      (__hip_bfloat16*)(ws + 256 + 2 * BB * HH * sizeof(__hip_bfloat16));
  hipMemsetAsync(d_ws, 0, 256 + 2 * BB * HH * sizeof(__hip_bfloat16), stream);

  convert_x_kernel<<<BB * SS, II, 0, stream>>>(x, xb);
  lstm_persistent<<<NWG, 256, 0, stream>>>(W, U, bias, xb, hbuf, ctr, out);
}

// Round 3
// 3134.107 us; speedup vs baseline: 2.7641x; 1.0490x over previous
//
#include <hip/hip_runtime.h>
#include <hip/hip_bf16.h>

// Problem: B=64, S=512, I=256, H=512 LSTM forward.
// R3: persistent kernel, 64 WGs. Cross-WG sync = distributed per-WG epoch
// flags (one 128B line per producer), replacing R2's single contended
// counter (64 serialized RMWs/step on one hot LLC line was ~3-6 us/step).
// Consumers: each wave's 64 lanes poll all 64 flags in ONE vector load +
// __all. All cross-WG data (h) moves via sc1 relaxed agent-scope atomics
// (LLC-coherent, no buffer_wbl2/inv). h double-buffered: flag[p]=t+1
// certifies p published h(t) AND finished reading h(t-1), so a producer at
// t+2 (overwriting buffer t&1) can only proceed once all read h(t). Safe.

#define BB 64
#define SS 512
#define II 256
#define HH 512
#define G4 2048
#define NWG 64
#define HJ 8    // hidden units per WG
#define NC 32   // gate columns per WG = 4*HJ

typedef __attribute__((ext_vector_type(8))) short bf16x8;
typedef __attribute__((ext_vector_type(4))) float f32x4;

// x [b][t][i] fp32 -> xb [t][b][i] bf16 (per-step A-operand layout)
__global__ void convert_x_kernel(const float* __restrict__ x,
                                 __hip_bfloat16* __restrict__ xb) {
  int blk = blockIdx.x;          // b*SS + t
  int b = blk >> 9;
  int t = blk & (SS - 1);
  int i = threadIdx.x;           // 0..255
  float v = x[(size_t)blk * II + i];
  xb[((size_t)t * BB + b) * II + i] = __float2bfloat16(v);
}

// LLC-coherent (agent-scope, sc1) relaxed accessors — no cache maintenance.
__device__ __forceinline__ unsigned long long ld_llc_u64(const void* p) {
  return __hip_atomic_load((unsigned long long*)p, __ATOMIC_RELAXED,
                           __HIP_MEMORY_SCOPE_AGENT);
}
__device__ __forceinline__ bf16x8 ld_llc_bf16x8(const __hip_bfloat16* p) {
  union { unsigned long long q[2]; bf16x8 v; } u;
  u.q[0] = ld_llc_u64(p);
  u.q[1] = ld_llc_u64(p + 4);   // +8 bytes
  return u.v;
}
__device__ __forceinline__ void st_llc_u32(unsigned int* p, unsigned int v) {
  __hip_atomic_store(p, v, __ATOMIC_RELAXED, __HIP_MEMORY_SCOPE_AGENT);
}
__device__ __forceinline__ unsigned int ld_llc_u32(const unsigned int* p) {
  return __hip_atomic_load((unsigned int*)p, __ATOMIC_RELAXED,
                           __HIP_MEMORY_SCOPE_AGENT);
}

__global__ __launch_bounds__(256, 1)
void lstm_persistent(const float* __restrict__ W,
                     const float* __restrict__ U,
                     const float* __restrict__ bias,
                     const __hip_bfloat16* __restrict__ xb,
                     __hip_bfloat16* __restrict__ hbuf,   // [2][BB][HH]
                     unsigned int* __restrict__ flags,    // [NWG] stride 32 u32 (128B)
                     float* __restrict__ out) {
  __shared__ alignas(16) __hip_bfloat16 Ut[NC][HH + 8];
  __shared__ alignas(16) __hip_bfloat16 Wt[NC][II + 8];
  __shared__ float gate[BB][NC + 1];
  __shared__ float bia[NC];

  const int tid = threadIdx.x;
  const int wg = blockIdx.x;
  const int j0 = wg * HJ;

  // ---- one-time: stage U/W column slices (transposed, bf16) ----
  for (int idx = tid; idx < NC * HH; idx += 256) {
    int c = idx & (NC - 1);
    int k = idx >> 5;
    int g = c >> 3, j = c & 7;
    Ut[c][k] = __float2bfloat16(U[(size_t)k * G4 + g * HH + j0 + j]);
  }
  for (int idx = tid; idx < NC * II; idx += 256) {
    int c = idx & (NC - 1);
    int k = idx >> 5;
    int g = c >> 3, j = c & 7;
    Wt[c][k] = __float2bfloat16(W[(size_t)k * G4 + g * HH + j0 + j]);
  }
  if (tid < NC) {
    int g = tid >> 3, j = tid & 7;
    bia[tid] = bias[g * HH + j0 + j];
  }
  __syncthreads();

  const int wave = tid >> 6;
  const int lane = tid & 63;
  const int l16 = lane & 15;
  const int quad = lane >> 4;
  const int arow = wave * 16 + l16;   // batch row for A-fragment

  // per-thread cell state: pairs p = 2*tid, 2*tid+1 share b; j consecutive
  float c0 = 0.f, c1 = 0.f;
  const int pb = (2 * tid) >> 3;      // batch
  const int pj = (2 * tid) & 7;       // even unit index; pair is (pj, pj+1)

  unsigned int* myflag = flags + wg * 32;     // own 128B line
  unsigned int* pollflag = flags + lane * 32; // lane i watches producer i

  for (int t = 0; t < SS; ++t) {
    const __hip_bfloat16* xt = xb + (size_t)t * (BB * II);

    // bias folded into accumulator init (D row=batch, col=gate-col=l16)
    float b0 = bia[l16], b1 = bia[16 + l16];
    f32x4 acc0 = {b0, b0, b0, b0};  // cols 0..15  (gates i,f)
    f32x4 acc1 = {b1, b1, b1, b1};  // cols 16..31 (gates g,o)

    // ---- x @ W : independent of h(t-1) -> before the flag wait ----
#pragma unroll
    for (int ks = 0; ks < II / 32; ++ks) {
      bf16x8 a = *(const bf16x8*)(xt + (size_t)arow * II + ks * 32 + quad * 8);
      bf16x8 fb0 = *(const bf16x8*)(&Wt[l16][ks * 32 + quad * 8]);
      bf16x8 fb1 = *(const bf16x8*)(&Wt[16 + l16][ks * 32 + quad * 8]);
      acc0 = __builtin_amdgcn_mfma_f32_16x16x32_bf16(a, fb0, acc0, 0, 0, 0);
      acc1 = __builtin_amdgcn_mfma_f32_16x16x32_bf16(a, fb1, acc1, 0, 0, 0);
    }

    // ---- wait: every producer published h(t-1). Each wave polls all 64
    // flags with one vector load (lane i -> flag[i]); no RMW, no sharing
    // on the write side. ----
    if (t > 0) {
      while (!__all(ld_llc_u32(pollflag) >= (unsigned)t)) {
      }
    }

    const __hip_bfloat16* hread = hbuf + (size_t)((t & 1) ^ 1) * (BB * HH);
    __hip_bfloat16* hwrite = hbuf + (size_t)(t & 1) * (BB * HH);

    // ---- h @ U : prefetch ALL fragments first (pipelined LLC loads),
    // then the MFMA chain (no per-chunk waitcnt serialization) ----
    bf16x8 hreg[HH / 32];
#pragma unroll
    for (int ks = 0; ks < HH / 32; ++ks)
      hreg[ks] = ld_llc_bf16x8(hread + (size_t)arow * HH + ks * 32 + quad * 8);
#pragma unroll
    for (int ks = 0; ks < HH / 32; ++ks) {
      bf16x8 fb0 = *(const bf16x8*)(&Ut[l16][ks * 32 + quad * 8]);
      bf16x8 fb1 = *(const bf16x8*)(&Ut[16 + l16][ks * 32 + quad * 8]);
      acc0 = __builtin_amdgcn_mfma_f32_16x16x32_bf16(hreg[ks], fb0, acc0, 0, 0, 0);
      acc1 = __builtin_amdgcn_mfma_f32_16x16x32_bf16(hreg[ks], fb1, acc1, 0, 0, 0);
    }

    // D layout (verified m89): row = quad*4 + reg, col = lane&15
#pragma unroll
    for (int r = 0; r < 4; ++r) {
      int row = wave * 16 + quad * 4 + r;
      gate[row][l16] = acc0[r];
      gate[row][16 + l16] = acc1[r];
    }
    __syncthreads();

    // ---- elementwise cell update: 2 (b,j) pairs per thread ----
    float hv[2];
#pragma unroll
    for (int s = 0; s < 2; ++s) {
      int j = pj + s;
      float& cst = s ? c1 : c0;
      float xi = gate[pb][j];
      float xf = gate[pb][8 + j];
      float xg = gate[pb][16 + j];
      float xo = gate[pb][24 + j];
      float it = 1.f / (1.f + __expf(-xi));
      float ft = 1.f / (1.f + __expf(-xf));
      float gx = fminf(fmaxf(xg, -15.f), 15.f);
      float eg = __expf(2.f * gx);
      float gt = (eg - 1.f) / (eg + 1.f);
      float ot = 1.f / (1.f + __expf(-xo));
      cst = ft * cst + it * gt;
      float cc = fminf(fmaxf(cst, -15.f), 15.f);
      float ec = __expf(2.f * cc);
      float th = (ec - 1.f) / (ec + 1.f);
      hv[s] = ot * th;
    }
    // publish h(t): packed 2xbf16 via sc1 relaxed atomic store
    union { __hip_bfloat16 b[2]; unsigned int u; } hp;
    hp.b[0] = __float2bfloat16(hv[0]);
    hp.b[1] = __float2bfloat16(hv[1]);
    st_llc_u32((unsigned int*)(hwrite + (size_t)pb * HH + j0 + pj), hp.u);
    // hidden_seq output (plain stores; flushed at kernel end)
    *(float2*)(out + (size_t)pb * (SS * HH) + (size_t)t * HH + j0 + pj) =
        make_float2(hv[0], hv[1]);
    if (t == SS - 1) {
      size_t base = (size_t)BB * SS * HH;
      *(float2*)(out + base + (size_t)pb * HH + j0 + pj) =
          make_float2(hv[0], hv[1]);                       // h_f
      *(float2*)(out + base + (size_t)BB * HH + (size_t)pb * HH + j0 + pj) =
          make_float2(c0, c1);                             // c_f
    }

    // ---- arrive: barrier drains all waves' stores (compiler emits
    // s_waitcnt vmcnt(0) before s_barrier), then one flag store ----
    if (t < SS - 1) {
      __syncthreads();
      if (tid == 0) st_llc_u32(myflag, (unsigned)(t + 1));
    }
  }
}

extern "C" void kernel_launch(void* const* d_in, const int* in_sizes, int n_in,
                              void* d_out, int out_size, void* d_ws, size_t ws_size,
                              hipStream_t stream) {
  const float* x = (const float*)d_in[0];     // [64,512,256]
  const float* W = (const float*)d_in[1];     // [256,2048]
  const float* U = (const float*)d_in[2];     // [512,2048]
  const float* bias = (const float*)d_in[3];  // [2048]
  float* out = (float*)d_out;

  char* ws = (char*)d_ws;
  unsigned int* flags = (unsigned int*)ws;                     // 64*128B = 8KB
  __hip_bfloat16* hbuf = (__hip_bfloat16*)(ws + 8192);         // 128 KB
  __hip_bfloat16* xb =
      (__hip_bfloat16*)(ws + 8192 + 2 * BB * HH * sizeof(__hip_bfloat16));
  // zero flags + hbuf (h(-1)=0); ws is re-poisoned to 0xAA each launch
  hipMemsetAsync(d_ws, 0, 8192 + 2 * BB * HH * sizeof(__hip_bfloat16), stream);

  convert_x_kernel<<<BB * SS, II, 0, stream>>>(x, xb);
  lstm_persistent<<<NWG, 256, 0, stream>>>(W, U, bias, xb, hbuf, flags, out);
}